// Round 8
// baseline (1079825.684 us; speedup 1.0000x reference)
//
#include <hip/hip_runtime.h>

#define VSZ 512
#define LSEQ 128
#define NTHR 512
#define NBLK 256    // 8 row-groups x 32 v-slices
#define NGRP 8
#define GBLK 32
#define SPIN_MAX  (1u << 20)  // prologue barrier bound
#define SPIN_FAST (1u << 16)  // per-step flag-poll bound (~16ms worst case)

using short8  = __attribute__((ext_vector_type(8))) short;
using short4v = __attribute__((ext_vector_type(4))) short;
using floatx4 = __attribute__((ext_vector_type(4))) float;
using ull2v   = __attribute__((ext_vector_type(2))) unsigned long long;

static __device__ __forceinline__ short f2bf(float f) {
    union { float f; unsigned u; } v; v.f = f;
    unsigned u = v.u;
    unsigned r = (u + 0x7fffu + ((u >> 16) & 1u)) >> 16;
    return (short)r;
}
static __device__ __forceinline__ float bf2f(short s) {
    union { unsigned u; float f; } v; v.u = ((unsigned)(unsigned short)s) << 16;
    return v.f;
}
static __device__ __forceinline__ float fast_rcp(float x) { return __builtin_amdgcn_rcpf(x); }
static __device__ __forceinline__ float sigm(float x)   { return fast_rcp(1.0f + __expf(-x)); }
static __device__ __forceinline__ float tanh_f(float x) { return 1.0f - 2.0f * fast_rcp(__expf(2.0f * x) + 1.0f); }

// ---- data-plane accessors. F=true: XCD-L2 scope (sc0; placement-verified same-L2).
//      F=false: device scope (sc0 sc1; round-5 proven).
template<bool F> static __device__ __forceinline__ void ldx4f(floatx4& d, const float* p) {
    if constexpr (F) asm volatile("global_load_dwordx4 %0, %1, off sc0"     : "=v"(d) : "v"(p));
    else             asm volatile("global_load_dwordx4 %0, %1, off sc0 sc1" : "=v"(d) : "v"(p));
}
template<bool F> static __device__ __forceinline__ void ldx4u(ull2v& d, const unsigned long long* p) {
    if constexpr (F) asm volatile("global_load_dwordx4 %0, %1, off sc0"     : "=v"(d) : "v"(p));
    else             asm volatile("global_load_dwordx4 %0, %1, off sc0 sc1" : "=v"(d) : "v"(p));
}
template<bool F> static __device__ __forceinline__ void ldx4s(short8& d, const short* p) {
    if constexpr (F) asm volatile("global_load_dwordx4 %0, %1, off sc0"     : "=v"(d) : "v"(p));
    else             asm volatile("global_load_dwordx4 %0, %1, off sc0 sc1" : "=v"(d) : "v"(p));
}
template<bool F> static __device__ __forceinline__ void stg16(void* p, unsigned v) {
    if constexpr (F) asm volatile("global_store_short %0, %1, off sc0"     :: "v"(p), "v"(v) : "memory");
    else             asm volatile("global_store_short %0, %1, off sc0 sc1" :: "v"(p), "v"(v) : "memory");
}
template<bool F> static __device__ __forceinline__ void stg32(void* p, unsigned v) {
    if constexpr (F) asm volatile("global_store_dword %0, %1, off sc0"     :: "v"(p), "v"(v) : "memory");
    else             asm volatile("global_store_dword %0, %1, off sc0 sc1" :: "v"(p), "v"(v) : "memory");
}
template<bool F> static __device__ __forceinline__ void stg64(void* p, unsigned long long v) {
    if constexpr (F) asm volatile("global_store_dwordx2 %0, %1, off sc0"     :: "v"(p), "v"(v) : "memory");
    else             asm volatile("global_store_dwordx2 %0, %1, off sc0 sc1" :: "v"(p), "v"(v) : "memory");
}

// ---- control plane device-scope primitives (round-5 proven)
static __device__ __forceinline__ unsigned atomic_add_dev(unsigned* p, unsigned v) {
    unsigned old;
    asm volatile("global_atomic_add %0, %1, %2, off sc0 sc1\n\ts_waitcnt vmcnt(0)"
                 : "=v"(old) : "v"(p), "v"(v) : "memory");
    return old;
}
static __device__ __forceinline__ unsigned ld_dev_u32(const unsigned* p) {
    unsigned v;
    asm volatile("global_load_dword %0, %1, off sc0 sc1\n\ts_waitcnt vmcnt(0)"
                 : "=v"(v) : "v"(p) : "memory");
    return v;
}

// per-step barrier. F=true: flag-based, XCD-local (sc0). Each block stores its own
// slot (no RMW, no ABA: monotonic t+1); wave 0's lanes 0..31 poll all 32 flags.
// Cross-replay staleness handled by in-kernel owner-zero before the prologue barrier.
// F=false: device-scope counter barrier (round-5/7 proven).
template<bool F>
static __device__ __forceinline__ void step_barrier(unsigned* cnt, unsigned* gen,
                                                    unsigned* fl, int j, int t, int tid) {
    asm volatile("s_waitcnt vmcnt(0)" ::: "memory");   // this wave's data stores are in L2
    __builtin_amdgcn_s_barrier();                       // => all waves' stores are in L2
    if constexpr (F) {
        if (tid < 64) {                                 // wave 0 only
            if (tid == 0) stg32<true>(fl + j, (unsigned)(t + 1));
            unsigned it = 0;
            for (;;) {
                unsigned v = 0u;
                if (tid < 32)
                    asm volatile("global_load_dword %0, %1, off sc0\n\ts_waitcnt vmcnt(0)"
                                 : "=v"(v) : "v"(fl + tid) : "memory");
                bool okl = (tid < 32) ? (v >= (unsigned)(t + 1)) : true;
                if (__all(okl)) break;
                if (++it > SPIN_FAST) break;            // fail visibly, not by timeout
                __builtin_amdgcn_s_sleep(1);
            }
        }
    } else {
        if (tid == 0) {
            unsigned old = atomic_add_dev(cnt, 1u);
            if ((old & (GBLK - 1)) == (GBLK - 1)) atomic_add_dev(gen, 1u);
            unsigned it = 0;
            while (ld_dev_u32(gen) < (unsigned)(t + 1)) {
                if (++it > SPIN_MAX) break;
                __builtin_amdgcn_s_sleep(1);
            }
        }
    }
    __builtin_amdgcn_s_barrier();
}

// device-scope two-level grid barrier (prologue only; round-5 proven)
static __device__ __forceinline__ void grid_barrier_dev(unsigned* ctrl, int tid, int bid) {
    asm volatile("s_waitcnt vmcnt(0)" ::: "memory");
    __builtin_amdgcn_s_barrier();
    if (tid == 0) {
        unsigned* l1   = ctrl + 256 + (bid >> 4) * 32;
        unsigned* root = ctrl + 768;
        unsigned* gen  = ctrl + 800;
        unsigned old = atomic_add_dev(l1, 1u);
        if ((old & 15) == 15) {
            unsigned rold = atomic_add_dev(root, 1u);
            if ((rold & 15) == 15) atomic_add_dev(gen, 1u);
        }
        unsigned it = 0;
        while (ld_dev_u32(gen) < 1u) {
            if (++it > SPIN_MAX) break;
            __builtin_amdgcn_s_sleep(1);
        }
    }
    __builtin_amdgcn_s_barrier();
}

// ---- prep: W_hh (f32 [2048][512]) -> bf16 B-fragments. Tile T = vt*64 + k*4 + g;
// lane l holds W_hh[g*512 + vt*16 + (l&15)][k*32 + (l>>4)*8 + 0..7].
__global__ void prep_wb(const float* __restrict__ Whh, short* __restrict__ Wb) {
    int tid = threadIdx.x;
    int lane = tid & 63;
    int T = blockIdx.x * 8 + (tid >> 6);
    int g  = T & 3;
    int k  = (T >> 2) & 15;
    int vt = T >> 6;
    int l15 = lane & 15, lg = lane >> 4;
    const float* src = Whh + (size_t)(g * 512 + vt * 16 + l15) * 512 + k * 32 + lg * 8;
    short8 o;
#pragma unroll
    for (int i = 0; i < 8; ++i) o[i] = f2bf(src[i]);
    *(short8*)(Wb + (size_t)T * 512 + lane * 8) = o;
}

// ---- prep: W_xb[a][v][g] = bf16( W_ih[g*512+v][a] + b_ih[j] + b_hh[j] )
__global__ void prep_wxb(const float* __restrict__ Wih, const float* __restrict__ bih,
                         const float* __restrict__ bhh, short* __restrict__ Wxb) {
    __shared__ float tile[64][65];
    int j0 = blockIdx.x * 64;
    int a0 = blockIdx.y * 64;
    int tid = threadIdx.x;
    for (int i = tid; i < 4096; i += NTHR) {
        int r = i >> 6, c = i & 63;
        int jj = j0 + r;
        tile[r][c] = Wih[(size_t)jj * 512 + a0 + c] + bih[jj] + bhh[jj];
    }
    __syncthreads();
    int v0 = j0 & 511;
    for (int i = tid; i < 4096; i += NTHR) {
        int r = i >> 6, c = i & 63;
        Wxb[(((size_t)(a0 + r)) * 512 + v0 + c) * 4 + (j0 >> 9)] = f2bf(tile[c][r]);
    }
}

// ---- templated step loop (identical numerics both paths; only sync/scope differ)
template<bool F>
static __device__ __forceinline__ void run_decoder(
    const float* __restrict__ x, const short* __restrict__ Wb, const short* __restrict__ Wxb,
    float* __restrict__ out,
    short* hbuf, float* psum, unsigned long long* pmax,
    unsigned* cnt, unsigned* gen, unsigned* fl,
    short (*hlds)[520], float (*gl)[4][17], float* rinvL, int* aidL,
    int tid, int g, int j) {

    const int lane = tid & 63;
    const int w    = tid >> 6;
    const int l15  = lane & 15;
    const int lg   = lane >> 4;
    const int v16  = tid & 15;
    const int rr   = tid >> 4;
    const int row0g = g * 64;
    const int jv   = j * 16 + v16;
    const int mt = w >> 1, g0 = (w & 1) * 2;

    // B fragments live in REGISTERS for the whole kernel (128 VGPRs):
    // bb[kc][gg] = Wb[(j*64 + kc*4 + g0+gg)*512 + lane*8 ..+8]
    short8 bb[16][2];
#pragma unroll
    for (int kc = 0; kc < 16; ++kc)
#pragma unroll
        for (int gg = 0; gg < 2; ++gg)
            bb[kc][gg] = *(const short8*)(Wb + ((size_t)j * 64 + kc * 4 + g0 + gg) * 512 + lane * 8);

    float cst[2] = {0.f, 0.f};
    float exv[2] = {0.f, 0.f};

    for (int t = 0; t < LSEQ - 1; ++t) {
        // ---- phase 1: read prev-step partials + h tile (one vmcnt drain) ----
        if (t == 0) {
            if (tid < 64) aidL[tid] = 1;              // SOS
#pragma unroll
            for (int p = 0; p < 8; ++p) {
                int row = (tid >> 6) + 8 * p;
                const float* src = x + (size_t)(row0g + row) * VSZ + (tid & 63) * 8;
                short8 v;
#pragma unroll
                for (int e = 0; e < 8; ++e) v[e] = f2bf(src[e]);
                *(short8*)&hlds[row][(tid & 63) * 8] = v;
            }
        } else {
            const int tb = (t + 1) & 1;
            floatx4 s4v; ull2v m2a, m2b;
            const float* ps = psum + ((size_t)tb * 512 + row0g) * 32 + tid * 4;
            const unsigned long long* pm = pmax + ((size_t)tb * 512 + row0g) * 32 + tid * 4;
            ldx4f<F>(s4v, ps);
            ldx4u<F>(m2a, pm);
            ldx4u<F>(m2b, pm + 2);
            short8 stg[8];
            const short* hsrc = hbuf + (size_t)tb * (VSZ * VSZ);
#pragma unroll
            for (int p = 0; p < 8; ++p) {
                int row = (tid >> 6) + 8 * p;
                ldx4s<F>(stg[p], hsrc + (size_t)(row0g + row) * VSZ + (tid & 63) * 8);
            }
            asm volatile("s_waitcnt vmcnt(0)" ::: "memory");
            __builtin_amdgcn_sched_barrier(0);
#pragma unroll
            for (int p = 0; p < 8; ++p) {
                int row = (tid >> 6) + 8 * p;
                *(short8*)&hlds[row][(tid & 63) * 8] = stg[p];
            }
            float s = (s4v[0] + s4v[1]) + (s4v[2] + s4v[3]);
            unsigned long long m = m2a[0] > m2a[1] ? m2a[0] : m2a[1];
            unsigned long long m2 = m2b[0] > m2b[1] ? m2b[0] : m2b[1];
            if (m2 > m) m = m2;
#pragma unroll
            for (int d = 1; d < 8; d <<= 1) {
                s += __shfl_xor(s, d);
                unsigned long long mo = __shfl_xor(m, d);
                if (mo > m) m = mo;
            }
            if ((tid & 7) == 0) {
                int r = tid >> 3;
                rinvL[r] = 1.0f / s;
                aidL[r]  = (int)(~(unsigned)m);
            }
        }
        __syncthreads();

        // ---- prefetch one-hot gathers for this step (drained before phase 3) ----
        short4v wxv0, wxv1;
        {
            const short* gp0 = Wxb + ((size_t)aidL[rr]      * VSZ + jv) * 4;
            const short* gp1 = Wxb + ((size_t)aidL[rr + 32] * VSZ + jv) * 4;
            asm volatile("global_load_dwordx2 %0, %1, off" : "=v"(wxv0) : "v"(gp0));
            asm volatile("global_load_dwordx2 %0, %1, off" : "=v"(wxv1) : "v"(gp1));
        }

        // ---- phase 2: probas for step t-1 ----
        if (t > 0) {
#pragma unroll
            for (int s2 = 0; s2 < 2; ++s2) {
                int r = rr + 32 * s2;
                __builtin_nontemporal_store(exv[s2] * rinvL[r],
                    &out[((size_t)(row0g + r) * LSEQ + (t - 1)) * VSZ + jv]);
            }
        }

        // ---- MFMA: gates[64 rows][2 gates x 16 v] per wave; B from registers ----
        floatx4 a0v = {0,0,0,0}, a1v = {0,0,0,0};
#pragma unroll
        for (int kc = 0; kc < 16; ++kc) {
            short8 av = *(const short8*)&hlds[mt * 16 + l15][kc * 32 + lg * 8];
            a0v = __builtin_amdgcn_mfma_f32_16x16x32_bf16(av, bb[kc][0], a0v, 0, 0, 0);
            a1v = __builtin_amdgcn_mfma_f32_16x16x32_bf16(av, bb[kc][1], a1v, 0, 0, 0);
        }
#pragma unroll
        for (int q = 0; q < 4; ++q) {
            gl[mt * 16 + lg * 4 + q][g0][l15]     = a0v[q];
            gl[mt * 16 + lg * 4 + q][g0 + 1][l15] = a1v[q];
        }
        __syncthreads();

        // ---- phase 3: pointwise LSTM + partials + h store ----
        asm volatile("s_waitcnt vmcnt(0)" ::: "memory");   // wxv (and old out stores) done
        __builtin_amdgcn_sched_barrier(0);
#pragma unroll
        for (int s2 = 0; s2 < 2; ++s2) {
            int r = rr + 32 * s2;
            short4v wxv = s2 ? wxv1 : wxv0;
            float gi = gl[r][0][v16] + bf2f(wxv[0]);
            float gf = gl[r][1][v16] + bf2f(wxv[1]);
            float gg = gl[r][2][v16] + bf2f(wxv[2]);
            float go = gl[r][3][v16] + bf2f(wxv[3]);
            float cn = sigm(gf) * cst[s2] + sigm(gi) * tanh_f(gg);
            cst[s2] = cn;
            float hn = sigm(go) * tanh_f(cn);
            stg16<F>(hbuf + (size_t)(t & 1) * (VSZ * VSZ) + (size_t)(row0g + r) * VSZ + jv,
                     (unsigned)(unsigned short)f2bf(hn));
            float e = __expf(hn);        // h in (-1,1): no max-subtraction needed
            exv[s2] = e;
            float s = e; float mv = e; int mi = jv;
#pragma unroll
            for (int m = 1; m < 16; m <<= 1) {
                s += __shfl_xor(s, m);
                float mv2 = __shfl_xor(mv, m);
                int   mi2 = __shfl_xor(mi, m);
                if (mv2 > mv || (mv2 == mv && mi2 < mi)) { mv = mv2; mi = mi2; }
            }
            if (v16 == 0) {
                size_t o32 = ((size_t)(t & 1) * 512 + row0g + r) * 32 + j;
                unsigned long long pk =
                    ((unsigned long long)__float_as_uint(mv) << 32) | (unsigned)(~(unsigned)mi);
                stg32<F>(psum + o32, __float_as_uint(s));
                stg64<F>(pmax + o32, pk);
            }
        }

        step_barrier<F>(cnt, gen, fl, j, t, tid);
    }

    // ---- epilogue: probas[126] + PAD column 127 (t=126 partials in tb=0) ----
    {
        floatx4 s4v;
        ldx4f<F>(s4v, psum + (size_t)row0g * 32 + tid * 4);
        asm volatile("s_waitcnt vmcnt(0)" ::: "memory");
        __builtin_amdgcn_sched_barrier(0);
        float s = (s4v[0] + s4v[1]) + (s4v[2] + s4v[3]);
#pragma unroll
        for (int d = 1; d < 8; d <<= 1) s += __shfl_xor(s, d);
        if ((tid & 7) == 0) rinvL[tid >> 3] = 1.0f / s;
    }
    __syncthreads();
#pragma unroll
    for (int s2 = 0; s2 < 2; ++s2) {
        int r = rr + 32 * s2;
        __builtin_nontemporal_store(exv[s2] * rinvL[r],
            &out[((size_t)(row0g + r) * LSEQ + (LSEQ - 2)) * VSZ + jv]);
        __builtin_nontemporal_store((jv == 0) ? 1.0f : 0.0f,
            &out[((size_t)(row0g + r) * LSEQ + (LSEQ - 1)) * VSZ + jv]);
    }
}

// ctrl layout (u32 idx): claim[g]=g*32 | pro_l1=256+i*32 | pro_root=768 | pro_gen=800
// group cnt/gen (slow path): 1024+g*64 / +32 | fast flags: 2048+g*128+j (32 u32/group)
__launch_bounds__(NTHR, 2)
__global__ void decoder_coop(const float* __restrict__ x, const short* __restrict__ Wb,
                             const short* __restrict__ Wxb,
                             short* hbuf_s, float* psum_s, unsigned long long* pmax_s,
                             short* hbuf_f, float* psum_f, unsigned long long* pmax_f,
                             unsigned* ctrl, float* __restrict__ out, int allow_fast) {
    __shared__ short hlds[64][520];
    __shared__ float gl[64][4][17];
    __shared__ float rinvL[64];
    __shared__ int   aidL[64];
    __shared__ int   sh_xcc, sh_slot, sh_ok;
    __shared__ unsigned sh_cnts[NGRP];

    const int tid = threadIdx.x;
    const int bid = blockIdx.x;

    // ---- prologue: claim a slot on my XCD; zero my flag slot (owner-zero kills any
    // sc0-dirty stale line from a previous graph replay); verify 32/32 placement ----
    if (tid == 0) {
        unsigned xcc;
        asm volatile("s_getreg_b32 %0, hwreg(HW_REG_XCC_ID)" : "=s"(xcc));
        xcc &= 7;
        unsigned slot = atomic_add_dev(ctrl + xcc * 32, 1u);
        sh_xcc = (int)xcc; sh_slot = (int)slot;
        if (slot < GBLK) stg32<true>(ctrl + 2048 + xcc * 128 + slot, 0u);
    }
    grid_barrier_dev(ctrl, tid, bid);
    if (tid < NGRP) sh_cnts[tid] = ld_dev_u32(ctrl + tid * 32);
    __syncthreads();
    if (tid == 0) {
        int ok = allow_fast && (sh_slot < GBLK);
#pragma unroll
        for (int g = 0; g < NGRP; ++g) ok = ok && (sh_cnts[g] == GBLK);
        sh_ok = ok;
    }
    __syncthreads();
    const int ok = sh_ok;
    const int g = ok ? sh_xcc : (bid & 7);
    const int j = ok ? sh_slot : (bid >> 3);

    if (ok)
        run_decoder<true >(x, Wb, Wxb, out, hbuf_f, psum_f, pmax_f,
                           ctrl + 1024 + g * 64, ctrl + 1024 + g * 64 + 32,
                           ctrl + 2048 + g * 128,
                           hlds, gl, rinvL, aidL, tid, g, j);
    else
        run_decoder<false>(x, Wb, Wxb, out, hbuf_s, psum_s, pmax_s,
                           ctrl + 1024 + g * 64, ctrl + 1024 + g * 64 + 32,
                           ctrl + 2048 + g * 128,
                           hlds, gl, rinvL, aidL, tid, g, j);
}

extern "C" void kernel_launch(void* const* d_in, const int* in_sizes, int n_in,
                              void* d_out, int out_size, void* d_ws, size_t ws_size,
                              hipStream_t stream) {
    const float* x    = (const float*)d_in[0];
    const float* W_ih = (const float*)d_in[1];
    const float* W_hh = (const float*)d_in[2];
    const float* b_ih = (const float*)d_in[3];
    const float* b_hh = (const float*)d_in[4];

    char* ws = (char*)d_ws;
    short* Wb     = (short*)ws;                                    // 2 MB
    short* Wxb    = (short*)(ws + (2u << 20));                     // 2 MB
    short* hbuf_s = (short*)(ws + (4u << 20));                     // 1 MB
    float* psum_s = (float*)(ws + (5u << 20));                     // 128 KB
    unsigned long long* pmax_s = (unsigned long long*)(ws + (5u << 20) + (128u << 10)); // 256 KB
    unsigned* ctrl = (unsigned*)(ws + (5u << 20) + (384u << 10));  // 16 KB
    short* hbuf_f = (short*)(ws + (5u << 20) + (400u << 10));      // 1 MB
    float* psum_f = (float*)(ws + (6u << 20) + (400u << 10));      // 128 KB
    unsigned long long* pmax_f = (unsigned long long*)(ws + (6u << 20) + (528u << 10)); // 256 KB
    const size_t needed = (6ull << 20) + (784ull << 10);
    int allow_fast = (ws_size >= needed) ? 1 : 0;

    prep_wb<<<256, NTHR, 0, stream>>>(W_hh, Wb);
    prep_wxb<<<dim3(32, 8), NTHR, 0, stream>>>(W_ih, b_ih, b_hh, Wxb);
    hipMemsetAsync(ctrl, 0, 16384, stream);

    float* outp = (float*)d_out;
    void* args[] = { (void*)&x, (void*)&Wb, (void*)&Wxb,
                     (void*)&hbuf_s, (void*)&psum_s, (void*)&pmax_s,
                     (void*)&hbuf_f, (void*)&psum_f, (void*)&pmax_f,
                     (void*)&ctrl, (void*)&outp, (void*)&allow_fast };
    hipLaunchCooperativeKernel((const void*)decoder_coop, dim3(NBLK), dim3(NTHR),
                               args, 0, stream);
}

// Round 9
// 625.441 us; speedup vs baseline: 1726.5042x; 1726.5042x over previous
//
#include <hip/hip_runtime.h>

#define VSZ 512
#define LSEQ 128
#define NTHR 512
#define NBLK 256    // 8 row-groups x 32 v-slices
#define NGRP 8
#define GBLK 32
#define SPIN_MAX (1u << 20)   // bounded spin: fail visibly, never timeout

using short8  = __attribute__((ext_vector_type(8))) short;
using short4v = __attribute__((ext_vector_type(4))) short;
using floatx4 = __attribute__((ext_vector_type(4))) float;
using ull2v   = __attribute__((ext_vector_type(2))) unsigned long long;

static __device__ __forceinline__ short f2bf(float f) {
    union { float f; unsigned u; } v; v.f = f;
    unsigned u = v.u;
    unsigned r = (u + 0x7fffu + ((u >> 16) & 1u)) >> 16;
    return (short)r;
}
static __device__ __forceinline__ float bf2f(short s) {
    union { unsigned u; float f; } v; v.u = ((unsigned)(unsigned short)s) << 16;
    return v.f;
}
static __device__ __forceinline__ float fast_rcp(float x) { return __builtin_amdgcn_rcpf(x); }
static __device__ __forceinline__ float sigm(float x)   { return fast_rcp(1.0f + __expf(-x)); }
static __device__ __forceinline__ float tanh_f(float x) { return 1.0f - 2.0f * fast_rcp(__expf(2.0f * x) + 1.0f); }

// ---- data-plane accessors. F=true: XCD-L2 scope (sc0; placement-verified same-L2,
//      streaming addresses only — NEVER polled). F=false: device scope (sc0 sc1).
template<bool F> static __device__ __forceinline__ void ldx4f(floatx4& d, const float* p) {
    if constexpr (F) asm volatile("global_load_dwordx4 %0, %1, off sc0"     : "=v"(d) : "v"(p));
    else             asm volatile("global_load_dwordx4 %0, %1, off sc0 sc1" : "=v"(d) : "v"(p));
}
template<bool F> static __device__ __forceinline__ void ldx4u(ull2v& d, const unsigned long long* p) {
    if constexpr (F) asm volatile("global_load_dwordx4 %0, %1, off sc0"     : "=v"(d) : "v"(p));
    else             asm volatile("global_load_dwordx4 %0, %1, off sc0 sc1" : "=v"(d) : "v"(p));
}
template<bool F> static __device__ __forceinline__ void ldx4s(short8& d, const short* p) {
    if constexpr (F) asm volatile("global_load_dwordx4 %0, %1, off sc0"     : "=v"(d) : "v"(p));
    else             asm volatile("global_load_dwordx4 %0, %1, off sc0 sc1" : "=v"(d) : "v"(p));
}
template<bool F> static __device__ __forceinline__ void stg16(void* p, unsigned v) {
    if constexpr (F) asm volatile("global_store_short %0, %1, off sc0"     :: "v"(p), "v"(v) : "memory");
    else             asm volatile("global_store_short %0, %1, off sc0 sc1" :: "v"(p), "v"(v) : "memory");
}
template<bool F> static __device__ __forceinline__ void stg32(void* p, unsigned v) {
    if constexpr (F) asm volatile("global_store_dword %0, %1, off sc0"     :: "v"(p), "v"(v) : "memory");
    else             asm volatile("global_store_dword %0, %1, off sc0 sc1" :: "v"(p), "v"(v) : "memory");
}
template<bool F> static __device__ __forceinline__ void stg64(void* p, unsigned long long v) {
    if constexpr (F) asm volatile("global_store_dwordx2 %0, %1, off sc0"     :: "v"(p), "v"(v) : "memory");
    else             asm volatile("global_store_dwordx2 %0, %1, off sc0 sc1" :: "v"(p), "v"(v) : "memory");
}

// ---- control plane: device scope ONLY (sc0 sc1) — rounds 5/7 proven.
static __device__ __forceinline__ unsigned atomic_add_dev(unsigned* p, unsigned v) {
    unsigned old;
    asm volatile("global_atomic_add %0, %1, %2, off sc0 sc1\n\ts_waitcnt vmcnt(0)"
                 : "=v"(old) : "v"(p), "v"(v) : "memory");
    return old;
}
static __device__ __forceinline__ unsigned ld_dev_u32(const unsigned* p) {
    unsigned v;
    asm volatile("global_load_dword %0, %1, off sc0 sc1\n\ts_waitcnt vmcnt(0)"
                 : "=v"(v) : "v"(p) : "memory");
    return v;
}

// per-row-group barrier: 32 device-scope arrivals, monotonic, gen target t+1
static __device__ __forceinline__ void group_barrier(unsigned* cnt, unsigned* gen,
                                                     int t, int tid) {
    asm volatile("s_waitcnt vmcnt(0)" ::: "memory");   // data stores reached their cache level
    __builtin_amdgcn_s_barrier();
    if (tid == 0) {
        unsigned old = atomic_add_dev(cnt, 1u);
        if ((old & (GBLK - 1)) == (GBLK - 1)) atomic_add_dev(gen, 1u);
        unsigned it = 0;
        while (ld_dev_u32(gen) < (unsigned)(t + 1)) {
            if (++it > SPIN_MAX) break;
            __builtin_amdgcn_s_sleep(1);
        }
    }
    __builtin_amdgcn_s_barrier();
}

// device-scope two-level grid barrier (prologue only; round-5 proven)
static __device__ __forceinline__ void grid_barrier_dev(unsigned* ctrl, int tid, int bid) {
    asm volatile("s_waitcnt vmcnt(0)" ::: "memory");
    __builtin_amdgcn_s_barrier();
    if (tid == 0) {
        unsigned* l1   = ctrl + 256 + (bid >> 4) * 32;
        unsigned* root = ctrl + 768;
        unsigned* gen  = ctrl + 800;
        unsigned old = atomic_add_dev(l1, 1u);
        if ((old & 15) == 15) {
            unsigned rold = atomic_add_dev(root, 1u);
            if ((rold & 15) == 15) atomic_add_dev(gen, 1u);
        }
        unsigned it = 0;
        while (ld_dev_u32(gen) < 1u) {
            if (++it > SPIN_MAX) break;
            __builtin_amdgcn_s_sleep(1);
        }
    }
    __builtin_amdgcn_s_barrier();
}

// ---- prep: W_hh (f32 [2048][512]) -> bf16 B-fragments. Tile T = vt*64 + k*4 + g;
// lane l holds W_hh[g*512 + vt*16 + (l&15)][k*32 + (l>>4)*8 + 0..7].
__global__ void prep_wb(const float* __restrict__ Whh, short* __restrict__ Wb) {
    int tid = threadIdx.x;
    int lane = tid & 63;
    int T = blockIdx.x * 8 + (tid >> 6);
    int g  = T & 3;
    int k  = (T >> 2) & 15;
    int vt = T >> 6;
    int l15 = lane & 15, lg = lane >> 4;
    const float* src = Whh + (size_t)(g * 512 + vt * 16 + l15) * 512 + k * 32 + lg * 8;
    short8 o;
#pragma unroll
    for (int i = 0; i < 8; ++i) o[i] = f2bf(src[i]);
    *(short8*)(Wb + (size_t)T * 512 + lane * 8) = o;
}

// ---- prep: W_xb[a][v][g] = bf16( W_ih[g*512+v][a] + b_ih[j] + b_hh[j] )
__global__ void prep_wxb(const float* __restrict__ Wih, const float* __restrict__ bih,
                         const float* __restrict__ bhh, short* __restrict__ Wxb) {
    __shared__ float tile[64][65];
    int j0 = blockIdx.x * 64;
    int a0 = blockIdx.y * 64;
    int tid = threadIdx.x;
    for (int i = tid; i < 4096; i += NTHR) {
        int r = i >> 6, c = i & 63;
        int jj = j0 + r;
        tile[r][c] = Wih[(size_t)jj * 512 + a0 + c] + bih[jj] + bhh[jj];
    }
    __syncthreads();
    int v0 = j0 & 511;
    for (int i = tid; i < 4096; i += NTHR) {
        int r = i >> 6, c = i & 63;
        Wxb[(((size_t)(a0 + r)) * 512 + v0 + c) * 4 + (j0 >> 9)] = f2bf(tile[c][r]);
    }
}

// ---- templated step loop (identical numerics both paths; only data scope differs)
template<bool F>
static __device__ __forceinline__ void run_decoder(
    const float* __restrict__ x, const short* __restrict__ Wb, const short* __restrict__ Wxb,
    float* __restrict__ out,
    short* hbuf, float* psum, unsigned long long* pmax,
    unsigned* cnt, unsigned* gen,
    short (*hlds)[520], float (*gl)[4][17], float* rinvL, int* aidL,
    int tid, int g, int j) {

    const int lane = tid & 63;
    const int w    = tid >> 6;
    const int l15  = lane & 15;
    const int lg   = lane >> 4;
    const int v16  = tid & 15;
    const int rr   = tid >> 4;
    const int row0g = g * 64;
    const int jv   = j * 16 + v16;
    const int mt = w >> 1, g0 = (w & 1) * 2;

    // B fragments in REGISTERS for the whole kernel — asm loads so the compiler
    // CANNOT sink/rematerialize them (round-8 lesson: plain loads get sunk).
    // bb[kc][gg] = Wb[(j*64 + kc*4 + g0+gg)*512 + lane*8 ..+8]; gg stride = 1024B.
    short8 bb[16][2];
#pragma unroll
    for (int kc = 0; kc < 16; ++kc) {
        const short* p = Wb + ((size_t)j * 64 + kc * 4 + g0) * 512 + lane * 8;
        asm volatile("global_load_dwordx4 %0, %1, off"             : "=v"(bb[kc][0]) : "v"(p));
        asm volatile("global_load_dwordx4 %0, %1, off offset:1024" : "=v"(bb[kc][1]) : "v"(p));
    }
    asm volatile("s_waitcnt vmcnt(0)" ::: "memory");
    __builtin_amdgcn_sched_barrier(0);

    float cst[2] = {0.f, 0.f};
    float exv[2] = {0.f, 0.f};

    for (int t = 0; t < LSEQ - 1; ++t) {
        // ---- phase 1: partials first (drain early), h loads overlap the reduce ----
        if (t == 0) {
            if (tid < 64) aidL[tid] = 1;              // SOS
#pragma unroll
            for (int p = 0; p < 8; ++p) {
                int row = (tid >> 6) + 8 * p;
                const float* src = x + (size_t)(row0g + row) * VSZ + (tid & 63) * 8;
                short8 v;
#pragma unroll
                for (int e = 0; e < 8; ++e) v[e] = f2bf(src[e]);
                *(short8*)&hlds[row][(tid & 63) * 8] = v;
            }
        } else {
            const int tb = (t + 1) & 1;
            floatx4 s4v; ull2v m2a, m2b;
            const float* ps = psum + ((size_t)tb * 512 + row0g) * 32 + tid * 4;
            const unsigned long long* pm = pmax + ((size_t)tb * 512 + row0g) * 32 + tid * 4;
            ldx4f<F>(s4v, ps);
            ldx4u<F>(m2a, pm);
            ldx4u<F>(m2b, pm + 2);
            short8 stg[8];
            const short* hsrc = hbuf + (size_t)tb * (VSZ * VSZ);
#pragma unroll
            for (int p = 0; p < 8; ++p) {
                int row = (tid >> 6) + 8 * p;
                ldx4s<F>(stg[p], hsrc + (size_t)(row0g + row) * VSZ + (tid & 63) * 8);
            }
            // partials (3 oldest loads) done; 8 h-loads still in flight during reduce
            asm volatile("s_waitcnt vmcnt(8)" ::: "memory");
            __builtin_amdgcn_sched_barrier(0);
            float s = (s4v[0] + s4v[1]) + (s4v[2] + s4v[3]);
            unsigned long long m = m2a[0] > m2a[1] ? m2a[0] : m2a[1];
            unsigned long long m2 = m2b[0] > m2b[1] ? m2b[0] : m2b[1];
            if (m2 > m) m = m2;
#pragma unroll
            for (int d = 1; d < 8; d <<= 1) {
                s += __shfl_xor(s, d);
                unsigned long long mo = __shfl_xor(m, d);
                if (mo > m) m = mo;
            }
            if ((tid & 7) == 0) {
                int r = tid >> 3;
                rinvL[r] = 1.0f / s;
                aidL[r]  = (int)(~(unsigned)m);
            }
            asm volatile("s_waitcnt vmcnt(0)" ::: "memory");
            __builtin_amdgcn_sched_barrier(0);
#pragma unroll
            for (int p = 0; p < 8; ++p) {
                int row = (tid >> 6) + 8 * p;
                *(short8*)&hlds[row][(tid & 63) * 8] = stg[p];
            }
        }
        __syncthreads();

        // ---- prefetch one-hot gathers for this step (drained before phase 3) ----
        short4v wxv0, wxv1;
        {
            const short* gp0 = Wxb + ((size_t)aidL[rr]      * VSZ + jv) * 4;
            const short* gp1 = Wxb + ((size_t)aidL[rr + 32] * VSZ + jv) * 4;
            asm volatile("global_load_dwordx2 %0, %1, off" : "=v"(wxv0) : "v"(gp0));
            asm volatile("global_load_dwordx2 %0, %1, off" : "=v"(wxv1) : "v"(gp1));
        }

        // ---- phase 2: probas for step t-1 ----
        if (t > 0) {
#pragma unroll
            for (int s2 = 0; s2 < 2; ++s2) {
                int r = rr + 32 * s2;
                __builtin_nontemporal_store(exv[s2] * rinvL[r],
                    &out[((size_t)(row0g + r) * LSEQ + (t - 1)) * VSZ + jv]);
            }
        }

        // ---- MFMA: gates[64 rows][2 gates x 16 v] per wave; B from registers ----
        floatx4 a0v = {0,0,0,0}, a1v = {0,0,0,0};
#pragma unroll
        for (int kc = 0; kc < 16; ++kc) {
            short8 av = *(const short8*)&hlds[mt * 16 + l15][kc * 32 + lg * 8];
            a0v = __builtin_amdgcn_mfma_f32_16x16x32_bf16(av, bb[kc][0], a0v, 0, 0, 0);
            a1v = __builtin_amdgcn_mfma_f32_16x16x32_bf16(av, bb[kc][1], a1v, 0, 0, 0);
        }
#pragma unroll
        for (int q = 0; q < 4; ++q) {
            gl[mt * 16 + lg * 4 + q][g0][l15]     = a0v[q];
            gl[mt * 16 + lg * 4 + q][g0 + 1][l15] = a1v[q];
        }
        __syncthreads();

        // ---- phase 3: pointwise LSTM + partials + h store ----
        asm volatile("s_waitcnt vmcnt(0)" ::: "memory");   // wxv (and out stores) done
        __builtin_amdgcn_sched_barrier(0);
#pragma unroll
        for (int s2 = 0; s2 < 2; ++s2) {
            int r = rr + 32 * s2;
            short4v wxv = s2 ? wxv1 : wxv0;
            float gi = gl[r][0][v16] + bf2f(wxv[0]);
            float gf = gl[r][1][v16] + bf2f(wxv[1]);
            float gg = gl[r][2][v16] + bf2f(wxv[2]);
            float go = gl[r][3][v16] + bf2f(wxv[3]);
            float cn = sigm(gf) * cst[s2] + sigm(gi) * tanh_f(gg);
            cst[s2] = cn;
            float hn = sigm(go) * tanh_f(cn);
            stg16<F>(hbuf + (size_t)(t & 1) * (VSZ * VSZ) + (size_t)(row0g + r) * VSZ + jv,
                     (unsigned)(unsigned short)f2bf(hn));
            float e = __expf(hn);        // h in (-1,1): no max-subtraction needed
            exv[s2] = e;
            float s = e; float mv = e; int mi = jv;
#pragma unroll
            for (int m = 1; m < 16; m <<= 1) {
                s += __shfl_xor(s, m);
                float mv2 = __shfl_xor(mv, m);
                int   mi2 = __shfl_xor(mi, m);
                if (mv2 > mv || (mv2 == mv && mi2 < mi)) { mv = mv2; mi = mi2; }
            }
            if (v16 == 0) {
                size_t o32 = ((size_t)(t & 1) * 512 + row0g + r) * 32 + j;
                unsigned long long pk =
                    ((unsigned long long)__float_as_uint(mv) << 32) | (unsigned)(~(unsigned)mi);
                stg32<F>(psum + o32, __float_as_uint(s));
                stg64<F>(pmax + o32, pk);
            }
        }

        group_barrier(cnt, gen, t, tid);
    }

    // ---- epilogue: probas[126] + PAD column 127 (t=126 partials in tb=0) ----
    {
        floatx4 s4v;
        ldx4f<F>(s4v, psum + (size_t)row0g * 32 + tid * 4);
        asm volatile("s_waitcnt vmcnt(0)" ::: "memory");
        __builtin_amdgcn_sched_barrier(0);
        float s = (s4v[0] + s4v[1]) + (s4v[2] + s4v[3]);
#pragma unroll
        for (int d = 1; d < 8; d <<= 1) s += __shfl_xor(s, d);
        if ((tid & 7) == 0) rinvL[tid >> 3] = 1.0f / s;
    }
    __syncthreads();
#pragma unroll
    for (int s2 = 0; s2 < 2; ++s2) {
        int r = rr + 32 * s2;
        __builtin_nontemporal_store(exv[s2] * rinvL[r],
            &out[((size_t)(row0g + r) * LSEQ + (LSEQ - 2)) * VSZ + jv]);
        __builtin_nontemporal_store((jv == 0) ? 1.0f : 0.0f,
            &out[((size_t)(row0g + r) * LSEQ + (LSEQ - 1)) * VSZ + jv]);
    }
}

// ctrl layout (u32 idx): claim[g]=g*32 | pro_l1=256+i*32 | pro_root=768 | pro_gen=800
// group cnt/gen (both paths): 1024+g*64 / +32
__launch_bounds__(NTHR, 2)
__global__ void decoder_coop(const float* __restrict__ x, const short* __restrict__ Wb,
                             const short* __restrict__ Wxb,
                             short* hbuf_s, float* psum_s, unsigned long long* pmax_s,
                             short* hbuf_f, float* psum_f, unsigned long long* pmax_f,
                             unsigned* ctrl, float* __restrict__ out, int allow_fast) {
    __shared__ short hlds[64][520];
    __shared__ float gl[64][4][17];
    __shared__ float rinvL[64];
    __shared__ int   aidL[64];
    __shared__ int   sh_xcc, sh_slot, sh_ok;
    __shared__ unsigned sh_cnts[NGRP];

    const int tid = threadIdx.x;
    const int bid = blockIdx.x;

    // ---- prologue: claim a slot on my XCD; verify 32/32 placement ----
    if (tid == 0) {
        unsigned xcc;
        asm volatile("s_getreg_b32 %0, hwreg(HW_REG_XCC_ID)" : "=s"(xcc));
        xcc &= 7;
        unsigned slot = atomic_add_dev(ctrl + xcc * 32, 1u);
        sh_xcc = (int)xcc; sh_slot = (int)slot;
    }
    grid_barrier_dev(ctrl, tid, bid);
    if (tid < NGRP) sh_cnts[tid] = ld_dev_u32(ctrl + tid * 32);
    __syncthreads();
    if (tid == 0) {
        int ok = allow_fast && (sh_slot < GBLK);
#pragma unroll
        for (int g = 0; g < NGRP; ++g) ok = ok && (sh_cnts[g] == GBLK);
        sh_ok = ok;
    }
    __syncthreads();
    const int ok = sh_ok;
    const int g = ok ? sh_xcc : (bid & 7);
    const int j = ok ? sh_slot : (bid >> 3);

    if (ok)
        run_decoder<true >(x, Wb, Wxb, out, hbuf_f, psum_f, pmax_f,
                           ctrl + 1024 + g * 64, ctrl + 1024 + g * 64 + 32,
                           hlds, gl, rinvL, aidL, tid, g, j);
    else
        run_decoder<false>(x, Wb, Wxb, out, hbuf_s, psum_s, pmax_s,
                           ctrl + 1024 + g * 64, ctrl + 1024 + g * 64 + 32,
                           hlds, gl, rinvL, aidL, tid, g, j);
}

extern "C" void kernel_launch(void* const* d_in, const int* in_sizes, int n_in,
                              void* d_out, int out_size, void* d_ws, size_t ws_size,
                              hipStream_t stream) {
    const float* x    = (const float*)d_in[0];
    const float* W_ih = (const float*)d_in[1];
    const float* W_hh = (const float*)d_in[2];
    const float* b_ih = (const float*)d_in[3];
    const float* b_hh = (const float*)d_in[4];

    char* ws = (char*)d_ws;
    short* Wb     = (short*)ws;                                    // 2 MB
    short* Wxb    = (short*)(ws + (2u << 20));                     // 2 MB
    short* hbuf_s = (short*)(ws + (4u << 20));                     // 1 MB
    float* psum_s = (float*)(ws + (5u << 20));                     // 128 KB
    unsigned long long* pmax_s = (unsigned long long*)(ws + (5u << 20) + (128u << 10)); // 256 KB
    unsigned* ctrl = (unsigned*)(ws + (5u << 20) + (384u << 10));  // 16 KB
    short* hbuf_f = (short*)(ws + (5u << 20) + (400u << 10));      // 1 MB
    float* psum_f = (float*)(ws + (6u << 20) + (400u << 10));      // 128 KB
    unsigned long long* pmax_f = (unsigned long long*)(ws + (6u << 20) + (528u << 10)); // 256 KB
    const size_t needed = (6ull << 20) + (784ull << 10);
    int allow_fast = (ws_size >= needed) ? 1 : 0;

    prep_wb<<<256, NTHR, 0, stream>>>(W_hh, Wb);
    prep_wxb<<<dim3(32, 8), NTHR, 0, stream>>>(W_ih, b_ih, b_hh, Wxb);
    hipMemsetAsync(ctrl, 0, 16384, stream);

    float* outp = (float*)d_out;
    void* args[] = { (void*)&x, (void*)&Wb, (void*)&Wxb,
                     (void*)&hbuf_s, (void*)&psum_s, (void*)&pmax_s,
                     (void*)&hbuf_f, (void*)&psum_f, (void*)&pmax_f,
                     (void*)&ctrl, (void*)&outp, (void*)&allow_fast };
    hipLaunchCooperativeKernel((const void*)decoder_coop, dim3(NBLK), dim3(NTHR),
                               args, 0, stream);
}